// Round 2
// baseline (733.663 us; speedup 1.0000x reference)
//
#include <hip/hip_runtime.h>
#include <hip/hip_bf16.h>

// SGC: out = log_softmax(relu(A_hat^3 (x W) + b))
// A_hat = D^-1/2 (A + I) D^-1/2 with edge weights = mean(edge_attr, axis=1)
// Key optimization: project x@W (256->64) BEFORE the 3 propagation hops (linearity),
// cutting gather/scatter traffic 4x. Propagation uses a dst-grouped CSR (built once
// per launch) so the scatter is atomic-free register accumulation, one wave per node.
// NOTE: harness delivers integer inputs as int32 (contract: "integer -> const int*").

#define F_IN 256
#define F_OUT 64

// ---------------- prep kernels ----------------

__global__ __launch_bounds__(256) void init_kernel(float* __restrict__ deg, int* __restrict__ cnt, int N) {
    int i = blockIdx.x * 256 + threadIdx.x;
    if (i < N) { deg[i] = 1.0f; cnt[i] = 0; }  // self-loop weight 1
}

// per edge: w = mean(edge_attr[e]); deg[dst] += w; cnt[dst] += 1
__global__ __launch_bounds__(256) void edgew_kernel(const float* __restrict__ ea,
                                                    const int* __restrict__ ei,
                                                    int E, int N, float* __restrict__ w,
                                                    float* __restrict__ deg, int* __restrict__ cnt) {
    int e = blockIdx.x * 256 + threadIdx.x;
    if (e >= E) return;
    const float4* a = (const float4*)(ea + (size_t)e * 8);
    float4 a0 = a[0], a1 = a[1];
    float wv = (a0.x + a0.y + a0.z + a0.w + a1.x + a1.y + a1.z + a1.w) * 0.125f;
    w[e] = wv;
    int d = ei[E + e];
    if ((unsigned)d >= (unsigned)N) return;  // defensive: never fault the container
    atomicAdd(&deg[d], wv);
    atomicAdd(&cnt[d], 1);
}

// 3-phase exclusive scan of cnt -> ptr (1024 elements per block)
__global__ __launch_bounds__(256) void scan1_kernel(const int* __restrict__ cnt, int* __restrict__ ptr,
                                                    int* __restrict__ bsum, int N) {
    __shared__ int s[256];
    int tid = threadIdx.x;
    int base = blockIdx.x * 1024 + tid * 4;
    int c0 = (base + 0 < N) ? cnt[base + 0] : 0;
    int c1 = (base + 1 < N) ? cnt[base + 1] : 0;
    int c2 = (base + 2 < N) ? cnt[base + 2] : 0;
    int c3 = (base + 3 < N) ? cnt[base + 3] : 0;
    int tsum = c0 + c1 + c2 + c3;
    s[tid] = tsum;
    __syncthreads();
    for (int off = 1; off < 256; off <<= 1) {
        int t = (tid >= off) ? s[tid - off] : 0;
        __syncthreads();
        s[tid] += t;
        __syncthreads();
    }
    int excl = s[tid] - tsum;
    if (base + 0 < N) ptr[base + 0] = excl;
    if (base + 1 < N) ptr[base + 1] = excl + c0;
    if (base + 2 < N) ptr[base + 2] = excl + c0 + c1;
    if (base + 3 < N) ptr[base + 3] = excl + c0 + c1 + c2;
    if (tid == 255) bsum[blockIdx.x] = s[255];
}

__global__ __launch_bounds__(256) void scan2_kernel(const int* __restrict__ bsum, int* __restrict__ bscan, int nb) {
    __shared__ int s[256];
    int tid = threadIdx.x;
    int v = (tid < nb) ? bsum[tid] : 0;
    s[tid] = v;
    __syncthreads();
    for (int off = 1; off < 256; off <<= 1) {
        int t = (tid >= off) ? s[tid - off] : 0;
        __syncthreads();
        s[tid] += t;
        __syncthreads();
    }
    if (tid < nb) bscan[tid] = s[tid] - v;
}

// ptr += block prefix; cursor = ptr; deg -> dinv (fused per-node pass)
__global__ __launch_bounds__(256) void scan3_kernel(int* __restrict__ ptr, const int* __restrict__ bscan,
                                                    int* __restrict__ cursor, float* __restrict__ deg, int N) {
    int i = blockIdx.x * 256 + threadIdx.x;
    if (i < N) {
        int p = ptr[i] + bscan[i >> 10];
        ptr[i] = p;
        cursor[i] = p;
        deg[i] = rsqrtf(deg[i]);  // deg >= 1 always (self-loop weight 1)
    }
}

// scatter edges into CSR slots, norm = dinv[src]*w*dinv[dst]
__global__ __launch_bounds__(256) void fill_kernel(const int* __restrict__ ei,
                                                   const float* __restrict__ w,
                                                   const float* __restrict__ dinv,
                                                   int* __restrict__ cursor,
                                                   int2* __restrict__ csr, int E, int N) {
    int e = blockIdx.x * 256 + threadIdx.x;
    if (e >= E) return;
    int s = ei[e];
    int d = ei[E + e];
    if ((unsigned)s >= (unsigned)N || (unsigned)d >= (unsigned)N) return;  // defensive
    float nrm = dinv[s] * w[e] * dinv[d];
    int slot = atomicAdd(&cursor[d], 1);
    csr[slot] = make_int2(s, __float_as_int(nrm));
}

// ---------------- y = x @ W  (256 -> 64), W staged in LDS ----------------
// wave handles 4 consecutive rows; lane = (r:2bit, jg:4bit): row-in-group r, col group jg (4 cols)
// W LDS layout is natural [k][64]: lane reads float4 at W[k][4*jg] -> 16 consecutive slots,
// 4-lane broadcast, conflict-free.
__global__ __launch_bounds__(256) void xw_kernel(const float* __restrict__ x, const float* __restrict__ W,
                                                 float* __restrict__ y, int N) {
    __shared__ float Wl[F_IN * F_OUT];  // 64 KB
    const float4* W4 = (const float4*)W;
    float4* Wl4 = (float4*)Wl;
    for (int i = threadIdx.x; i < F_IN * F_OUT / 4; i += 256) Wl4[i] = W4[i];
    __syncthreads();

    int wave = (blockIdx.x * 256 + threadIdx.x) >> 6;
    int nwaves = (gridDim.x * 256) >> 6;
    int lane = threadIdx.x & 63;
    int r = lane >> 4;
    int jg = lane & 15;
    int ngroups = (N + 3) >> 2;

    for (int g = wave; g < ngroups; g += nwaves) {
        int row = g * 4 + r;
        if (row >= N) continue;
        const float4* xr = (const float4*)(x + (size_t)row * F_IN);
        float ax = 0.f, ay = 0.f, az = 0.f, aw = 0.f;
#pragma unroll 4
        for (int k4 = 0; k4 < F_IN / 4; ++k4) {
            float4 xv = xr[k4];
            float4 w0 = Wl4[(k4 * 4 + 0) * 16 + jg];
            float4 w1 = Wl4[(k4 * 4 + 1) * 16 + jg];
            float4 w2 = Wl4[(k4 * 4 + 2) * 16 + jg];
            float4 w3 = Wl4[(k4 * 4 + 3) * 16 + jg];
            ax = fmaf(xv.x, w0.x, ax); ay = fmaf(xv.x, w0.y, ay); az = fmaf(xv.x, w0.z, az); aw = fmaf(xv.x, w0.w, aw);
            ax = fmaf(xv.y, w1.x, ax); ay = fmaf(xv.y, w1.y, ay); az = fmaf(xv.y, w1.z, az); aw = fmaf(xv.y, w1.w, aw);
            ax = fmaf(xv.z, w2.x, ax); ay = fmaf(xv.z, w2.y, ay); az = fmaf(xv.z, w2.z, az); aw = fmaf(xv.z, w2.w, aw);
            ax = fmaf(xv.w, w3.x, ax); ay = fmaf(xv.w, w3.y, ay); az = fmaf(xv.w, w3.z, az); aw = fmaf(xv.w, w3.w, aw);
        }
        float4 acc = {ax, ay, az, aw};
        ((float4*)(y + (size_t)row * F_OUT))[jg] = acc;
    }
}

// ---------------- propagation: one wave per node, lane = feature ----------------
__global__ __launch_bounds__(256) void prop_kernel(const float* __restrict__ hin, float* __restrict__ hout,
                                                   const int* __restrict__ ptr, const int* __restrict__ cnt,
                                                   const float* __restrict__ dinv,
                                                   const int2* __restrict__ csr, int N) {
    int node = blockIdx.x * 4 + (threadIdx.x >> 6);
    if (node >= N) return;
    int lane = threadIdx.x & 63;
    float di = dinv[node];
    float acc = di * di * hin[(size_t)node * 64 + lane];  // self-loop: dinv*1*dinv
    int p = ptr[node], c = cnt[node];
    int i = 0;
    for (; i + 4 <= c; i += 4) {
        int2 e0 = csr[p + i + 0];
        int2 e1 = csr[p + i + 1];
        int2 e2 = csr[p + i + 2];
        int2 e3 = csr[p + i + 3];
        float v0 = hin[(size_t)e0.x * 64 + lane];
        float v1 = hin[(size_t)e1.x * 64 + lane];
        float v2 = hin[(size_t)e2.x * 64 + lane];
        float v3 = hin[(size_t)e3.x * 64 + lane];
        acc = fmaf(__int_as_float(e0.y), v0, acc);
        acc = fmaf(__int_as_float(e1.y), v1, acc);
        acc = fmaf(__int_as_float(e2.y), v2, acc);
        acc = fmaf(__int_as_float(e3.y), v3, acc);
    }
    for (; i < c; ++i) {
        int2 e = csr[p + i];
        acc = fmaf(__int_as_float(e.y), hin[(size_t)e.x * 64 + lane], acc);
    }
    hout[(size_t)node * 64 + lane] = acc;
}

// ---------------- epilogue: +b, relu, log_softmax over 64 cols ----------------
__global__ __launch_bounds__(256) void finalize_kernel(float* __restrict__ h, const float* __restrict__ b, int N) {
    int node = blockIdx.x * 4 + (threadIdx.x >> 6);
    if (node >= N) return;
    int lane = threadIdx.x & 63;
    float v = h[(size_t)node * 64 + lane] + b[lane];
    v = fmaxf(v, 0.0f);
    float m = v;
    for (int off = 32; off; off >>= 1) m = fmaxf(m, __shfl_xor(m, off, 64));
    float ex = expf(v - m);
    float s = ex;
    for (int off = 32; off; off >>= 1) s += __shfl_xor(s, off, 64);
    h[(size_t)node * 64 + lane] = (v - m) - logf(s);
}

// ---------------- launch ----------------

extern "C" void kernel_launch(void* const* d_in, const int* in_sizes, int n_in,
                              void* d_out, int out_size, void* d_ws, size_t ws_size,
                              hipStream_t stream) {
    const float* x = (const float*)d_in[0];
    const float* edge_attr = (const float*)d_in[1];
    const float* W = (const float*)d_in[2];
    const float* b = (const float*)d_in[3];
    const int* ei = (const int*)d_in[4];   // harness delivers integer inputs as int32
    int N = in_sizes[0] / F_IN;
    int E = in_sizes[4] / 2;
    float* out = (float*)d_out;

    char* ws = (char*)d_ws;
    size_t off = 0;
    auto alloc = [&](size_t bytes) -> char* {
        char* p = ws + off;
        off += (bytes + 255) & ~(size_t)255;
        return p;
    };
    float* deg    = (float*)alloc((size_t)N * 4);   // becomes dinv in-place (scan3)
    int*   cnt    = (int*)alloc((size_t)N * 4);
    int*   ptr    = (int*)alloc((size_t)N * 4);
    int*   cursor = (int*)alloc((size_t)N * 4);
    int*   bsum   = (int*)alloc(256 * 4);
    int*   bscan  = (int*)alloc(256 * 4);
    float* w      = (float*)alloc((size_t)E * 4);
    int2*  csr    = (int2*)alloc((size_t)E * 8);
    float* h0     = (float*)alloc((size_t)N * 64 * 4);
    // total ~46 MB of ws

    int nbN = (N + 255) / 256;
    int nbE = (E + 255) / 256;
    int nb1024 = (N + 1023) / 1024;
    int nbNode4 = (N + 3) / 4;

    init_kernel<<<nbN, 256, 0, stream>>>(deg, cnt, N);
    edgew_kernel<<<nbE, 256, 0, stream>>>(edge_attr, ei, E, N, w, deg, cnt);
    scan1_kernel<<<nb1024, 256, 0, stream>>>(cnt, ptr, bsum, N);
    scan2_kernel<<<1, 256, 0, stream>>>(bsum, bscan, nb1024);
    scan3_kernel<<<nbN, 256, 0, stream>>>(ptr, bscan, cursor, deg, N);
    fill_kernel<<<nbE, 256, 0, stream>>>(ei, w, deg, cursor, csr, E, N);

    xw_kernel<<<1024, 256, 0, stream>>>(x, W, h0, N);

    // 3 hops, ping-pong h0 <-> d_out (d_out doubles as scratch)
    prop_kernel<<<nbNode4, 256, 0, stream>>>(h0, out, ptr, cnt, deg, csr, N);
    prop_kernel<<<nbNode4, 256, 0, stream>>>(out, h0, ptr, cnt, deg, csr, N);
    prop_kernel<<<nbNode4, 256, 0, stream>>>(h0, out, ptr, cnt, deg, csr, N);

    finalize_kernel<<<nbNode4, 256, 0, stream>>>(out, b, N);
}

// Round 4
// 727.628 us; speedup vs baseline: 1.0083x; 1.0083x over previous
//
#include <hip/hip_runtime.h>
#include <hip/hip_bf16.h>

// SGC: out = log_softmax(relu(A_hat^3 (x W) + b))
// A_hat = D^-1/2 (A + I) D^-1/2 with edge weights = mean(edge_attr, axis=1)
//
// Structure:
//  - project x@W (256->64) BEFORE the 3 hops (linearity) -> 4x less gather traffic
//  - propagate in scaled space g = D^-1/2 h:
//        g_{k+1}[d] = dinv[d]^2 * ( sum_e w_e * g_k[src] + g_k[d] ),  h_3 = g_3 / dinv
//    => CSR stores raw (src, w): no dinv needed at build time, so deg is computed
//       atomic-free by walking the finished CSR. Only remaining atomics: 2x1.6M int
//       (cnt histogram + cursor), which are memory-side RMW on MI355X (≈32B each).

#define F_IN 256
#define F_OUT 64

// ---------------- prep kernels ----------------

__global__ __launch_bounds__(256) void init_kernel(int* __restrict__ cnt, int N) {
    int i = blockIdx.x * 256 + threadIdx.x;
    if (i < N) cnt[i] = 0;
}

// per edge: w = mean(edge_attr[e]); cnt[dst] += 1   (int atomic only)
__global__ __launch_bounds__(256) void edgew_kernel(const float* __restrict__ ea,
                                                    const int* __restrict__ ei,
                                                    int E, int N, float* __restrict__ w,
                                                    int* __restrict__ cnt) {
    int e = blockIdx.x * 256 + threadIdx.x;
    if (e >= E) return;
    const float4* a = (const float4*)(ea + (size_t)e * 8);
    float4 a0 = a[0], a1 = a[1];
    float wv = (a0.x + a0.y + a0.z + a0.w + a1.x + a1.y + a1.z + a1.w) * 0.125f;
    w[e] = wv;
    int d = ei[E + e];
    if ((unsigned)d >= (unsigned)N) return;  // defensive: never fault the container
    atomicAdd(&cnt[d], 1);
}

// 3-phase exclusive scan of cnt -> ptr (1024 elements per block)
__global__ __launch_bounds__(256) void scan1_kernel(const int* __restrict__ cnt, int* __restrict__ ptr,
                                                    int* __restrict__ bsum, int N) {
    __shared__ int s[256];
    int tid = threadIdx.x;
    int base = blockIdx.x * 1024 + tid * 4;
    int c0 = (base + 0 < N) ? cnt[base + 0] : 0;
    int c1 = (base + 1 < N) ? cnt[base + 1] : 0;
    int c2 = (base + 2 < N) ? cnt[base + 2] : 0;
    int c3 = (base + 3 < N) ? cnt[base + 3] : 0;
    int tsum = c0 + c1 + c2 + c3;
    s[tid] = tsum;
    __syncthreads();
    for (int off = 1; off < 256; off <<= 1) {
        int t = (tid >= off) ? s[tid - off] : 0;
        __syncthreads();
        s[tid] += t;
        __syncthreads();
    }
    int excl = s[tid] - tsum;
    if (base + 0 < N) ptr[base + 0] = excl;
    if (base + 1 < N) ptr[base + 1] = excl + c0;
    if (base + 2 < N) ptr[base + 2] = excl + c0 + c1;
    if (base + 3 < N) ptr[base + 3] = excl + c0 + c1 + c2;
    if (tid == 255) bsum[blockIdx.x] = s[255];
}

__global__ __launch_bounds__(256) void scan2_kernel(const int* __restrict__ bsum, int* __restrict__ bscan, int nb) {
    __shared__ int s[256];
    int tid = threadIdx.x;
    int v = (tid < nb) ? bsum[tid] : 0;
    s[tid] = v;
    __syncthreads();
    for (int off = 1; off < 256; off <<= 1) {
        int t = (tid >= off) ? s[tid - off] : 0;
        __syncthreads();
        s[tid] += t;
        __syncthreads();
    }
    if (tid < nb) bscan[tid] = s[tid] - v;
}

// ptr += block prefix; cursor = ptr
__global__ __launch_bounds__(256) void scan3_kernel(int* __restrict__ ptr, const int* __restrict__ bscan,
                                                    int* __restrict__ cursor, int N) {
    int i = blockIdx.x * 256 + threadIdx.x;
    if (i < N) {
        int p = ptr[i] + bscan[i >> 10];
        ptr[i] = p;
        cursor[i] = p;
    }
}

// scatter edges into CSR slots: csr[slot] = (src, w_raw)   (no dinv dependency)
__global__ __launch_bounds__(256) void fill_kernel(const int* __restrict__ ei,
                                                   const float* __restrict__ w,
                                                   int* __restrict__ cursor,
                                                   int2* __restrict__ csr, int E, int N) {
    int e = blockIdx.x * 256 + threadIdx.x;
    if (e >= E) return;
    int s = ei[e];
    int d = ei[E + e];
    if ((unsigned)s >= (unsigned)N || (unsigned)d >= (unsigned)N) return;  // defensive
    int slot = atomicAdd(&cursor[d], 1);
    csr[slot] = make_int2(s, __float_as_int(w[e]));
}

// atomic-free degree: walk own CSR row. deg = 1 (self-loop) + sum w.
// thread per node; rows are contiguous in memory so reads stay L2/L3-hot.
__global__ __launch_bounds__(256) void degk_kernel(const int* __restrict__ ptr, const int* __restrict__ cnt,
                                                   const int2* __restrict__ csr,
                                                   float* __restrict__ dinv, float* __restrict__ sqrtdeg, int N) {
    int i = blockIdx.x * 256 + threadIdx.x;
    if (i >= N) return;
    int p = ptr[i], c = cnt[i];
    float deg = 1.0f;
    for (int j = 0; j < c; ++j) deg += __int_as_float(csr[p + j].y);
    dinv[i] = rsqrtf(deg);
    sqrtdeg[i] = sqrtf(deg);
}

// ---------------- g0 = dinv ⊙ (x @ W)  (256 -> 64), W staged in LDS ----------------
// wave handles 4 consecutive rows; lane = (r:2bit, jg:4bit)
__global__ __launch_bounds__(256) void xw_kernel(const float* __restrict__ x, const float* __restrict__ W,
                                                 const float* __restrict__ dinv,
                                                 float* __restrict__ y, int N) {
    __shared__ float Wl[F_IN * F_OUT];  // 64 KB
    const float4* W4 = (const float4*)W;
    float4* Wl4 = (float4*)Wl;
    for (int i = threadIdx.x; i < F_IN * F_OUT / 4; i += 256) Wl4[i] = W4[i];
    __syncthreads();

    int wave = (blockIdx.x * 256 + threadIdx.x) >> 6;
    int nwaves = (gridDim.x * 256) >> 6;
    int lane = threadIdx.x & 63;
    int r = lane >> 4;
    int jg = lane & 15;
    int ngroups = (N + 3) >> 2;

    for (int g = wave; g < ngroups; g += nwaves) {
        int row = g * 4 + r;
        if (row >= N) continue;
        const float4* xr = (const float4*)(x + (size_t)row * F_IN);
        float ax = 0.f, ay = 0.f, az = 0.f, aw = 0.f;
#pragma unroll 4
        for (int k4 = 0; k4 < F_IN / 4; ++k4) {
            float4 xv = xr[k4];
            float4 w0 = Wl4[(k4 * 4 + 0) * 16 + jg];
            float4 w1 = Wl4[(k4 * 4 + 1) * 16 + jg];
            float4 w2 = Wl4[(k4 * 4 + 2) * 16 + jg];
            float4 w3 = Wl4[(k4 * 4 + 3) * 16 + jg];
            ax = fmaf(xv.x, w0.x, ax); ay = fmaf(xv.x, w0.y, ay); az = fmaf(xv.x, w0.z, az); aw = fmaf(xv.x, w0.w, aw);
            ax = fmaf(xv.y, w1.x, ax); ay = fmaf(xv.y, w1.y, ay); az = fmaf(xv.y, w1.z, az); aw = fmaf(xv.y, w1.w, aw);
            ax = fmaf(xv.z, w2.x, ax); ay = fmaf(xv.z, w2.y, ay); az = fmaf(xv.z, w2.z, az); aw = fmaf(xv.z, w2.w, aw);
            ax = fmaf(xv.w, w3.x, ax); ay = fmaf(xv.w, w3.y, ay); az = fmaf(xv.w, w3.z, az); aw = fmaf(xv.w, w3.w, aw);
        }
        float di = dinv[row];
        float4 acc = {ax * di, ay * di, az * di, aw * di};
        ((float4*)(y + (size_t)row * F_OUT))[jg] = acc;
    }
}

// ---------------- propagation in g-space: one wave per node, lane = feature ----------------
// g_out[d] = dinv[d]^2 * ( sum_e w_e * g_in[src] + g_in[d] )
__global__ __launch_bounds__(256) void prop_kernel(const float* __restrict__ gin, float* __restrict__ gout,
                                                   const int* __restrict__ ptr, const int* __restrict__ cnt,
                                                   const float* __restrict__ dinv,
                                                   const int2* __restrict__ csr, int N) {
    int node = blockIdx.x * 4 + (threadIdx.x >> 6);
    if (node >= N) return;
    int lane = threadIdx.x & 63;
    float acc = gin[(size_t)node * 64 + lane];  // self-loop, weight 1
    int p = ptr[node], c = cnt[node];
    int i = 0;
    for (; i + 4 <= c; i += 4) {
        int2 e0 = csr[p + i + 0];
        int2 e1 = csr[p + i + 1];
        int2 e2 = csr[p + i + 2];
        int2 e3 = csr[p + i + 3];
        float v0 = gin[(size_t)e0.x * 64 + lane];
        float v1 = gin[(size_t)e1.x * 64 + lane];
        float v2 = gin[(size_t)e2.x * 64 + lane];
        float v3 = gin[(size_t)e3.x * 64 + lane];
        acc = fmaf(__int_as_float(e0.y), v0, acc);
        acc = fmaf(__int_as_float(e1.y), v1, acc);
        acc = fmaf(__int_as_float(e2.y), v2, acc);
        acc = fmaf(__int_as_float(e3.y), v3, acc);
    }
    for (; i < c; ++i) {
        int2 e = csr[p + i];
        acc = fmaf(__int_as_float(e.y), gin[(size_t)e.x * 64 + lane], acc);
    }
    float di = dinv[node];
    gout[(size_t)node * 64 + lane] = acc * di * di;
}

// ---------------- epilogue: h3 = g3*sqrt(deg); +b, relu, log_softmax over 64 cols ----------------
__global__ __launch_bounds__(256) void finalize_kernel(float* __restrict__ h, const float* __restrict__ b,
                                                       const float* __restrict__ sqrtdeg, int N) {
    int node = blockIdx.x * 4 + (threadIdx.x >> 6);
    if (node >= N) return;
    int lane = threadIdx.x & 63;
    float v = h[(size_t)node * 64 + lane] * sqrtdeg[node] + b[lane];
    v = fmaxf(v, 0.0f);
    float m = v;
    for (int off = 32; off; off >>= 1) m = fmaxf(m, __shfl_xor(m, off, 64));
    float ex = expf(v - m);
    float s = ex;
    for (int off = 32; off; off >>= 1) s += __shfl_xor(s, off, 64);
    h[(size_t)node * 64 + lane] = (v - m) - logf(s);
}

// ---------------- launch ----------------

extern "C" void kernel_launch(void* const* d_in, const int* in_sizes, int n_in,
                              void* d_out, int out_size, void* d_ws, size_t ws_size,
                              hipStream_t stream) {
    const float* x = (const float*)d_in[0];
    const float* edge_attr = (const float*)d_in[1];
    const float* W = (const float*)d_in[2];
    const float* b = (const float*)d_in[3];
    const int* ei = (const int*)d_in[4];   // harness delivers integer inputs as int32
    int N = in_sizes[0] / F_IN;
    int E = in_sizes[4] / 2;
    float* out = (float*)d_out;

    char* ws = (char*)d_ws;
    size_t off = 0;
    auto alloc = [&](size_t bytes) -> char* {
        char* p = ws + off;
        off += (bytes + 255) & ~(size_t)255;
        return p;
    };
    float* dinv    = (float*)alloc((size_t)N * 4);
    float* sqrtdeg = (float*)alloc((size_t)N * 4);
    int*   cnt     = (int*)alloc((size_t)N * 4);
    int*   ptr     = (int*)alloc((size_t)N * 4);
    int*   cursor  = (int*)alloc((size_t)N * 4);
    int*   bsum    = (int*)alloc(256 * 4);
    int*   bscan   = (int*)alloc(256 * 4);
    float* w       = (float*)alloc((size_t)E * 4);
    int2*  csr     = (int2*)alloc((size_t)E * 8);
    float* h0      = (float*)alloc((size_t)N * 64 * 4);
    // total ~46 MB of ws

    int nbN = (N + 255) / 256;
    int nbE = (E + 255) / 256;
    int nb1024 = (N + 1023) / 1024;
    int nbNode4 = (N + 3) / 4;

    init_kernel<<<nbN, 256, 0, stream>>>(cnt, N);
    edgew_kernel<<<nbE, 256, 0, stream>>>(edge_attr, ei, E, N, w, cnt);
    scan1_kernel<<<nb1024, 256, 0, stream>>>(cnt, ptr, bsum, N);
    scan2_kernel<<<1, 256, 0, stream>>>(bsum, bscan, nb1024);
    scan3_kernel<<<nbN, 256, 0, stream>>>(ptr, bscan, cursor, N);
    fill_kernel<<<nbE, 256, 0, stream>>>(ei, w, cursor, csr, E, N);
    degk_kernel<<<nbN, 256, 0, stream>>>(ptr, cnt, csr, dinv, sqrtdeg, N);

    xw_kernel<<<1024, 256, 0, stream>>>(x, W, dinv, h0, N);

    // 3 hops in g-space, ping-pong h0 <-> d_out (d_out doubles as scratch)
    prop_kernel<<<nbNode4, 256, 0, stream>>>(h0, out, ptr, cnt, dinv, csr, N);
    prop_kernel<<<nbNode4, 256, 0, stream>>>(out, h0, ptr, cnt, dinv, csr, N);
    prop_kernel<<<nbNode4, 256, 0, stream>>>(h0, out, ptr, cnt, dinv, csr, N);

    finalize_kernel<<<nbNode4, 256, 0, stream>>>(out, b, sqrtdeg, N);
}

// Round 5
// 641.888 us; speedup vs baseline: 1.1430x; 1.1336x over previous
//
#include <hip/hip_runtime.h>
#include <hip/hip_bf16.h>

// SGC: out = log_softmax(relu(A_hat^3 (x W) + b))
// A_hat = D^-1/2 (A + I) D^-1/2 with edge weights = mean(edge_attr, axis=1)
//
// Structure:
//  - project x@W (256->64) BEFORE the 3 hops (linearity) -> 4x less gather traffic
//  - propagate in scaled space g = D^-1/2 h:
//        g_{k+1}[d] = dinv[d]^2 * ( sum_e w_e * g_k[src] + g_k[d] ),  h_3 = g_3 / dinv
//    => CSR stores raw (src, w); deg computed atomic-free from the finished CSR.
//  - xw: register-blocked 4 rows x 4 cols per lane, 1024-thread blocks (one 64KB
//    W-stage serves 16 waves; 1 block/CU, ~16 waves/CU) -> LDS bytes/FMA down 4x.
//  - hop 3 fused with bias+relu+log_softmax epilogue (h3 = acc*dinv).

#define F_IN 256
#define F_OUT 64

// ---------------- prep kernels ----------------

__global__ __launch_bounds__(256) void init_kernel(int* __restrict__ cnt, int N) {
    int i = blockIdx.x * 256 + threadIdx.x;
    if (i < N) cnt[i] = 0;
}

// histogram of dst only (reads the second half of edge_index)
__global__ __launch_bounds__(256) void hist_kernel(const int* __restrict__ ei_dst,
                                                   int E, int N, int* __restrict__ cnt) {
    int e = blockIdx.x * 256 + threadIdx.x;
    if (e >= E) return;
    int d = ei_dst[e];
    if ((unsigned)d >= (unsigned)N) return;  // defensive: never fault the container
    atomicAdd(&cnt[d], 1);
}

// 3-phase exclusive scan of cnt -> ptr (1024 elements per block)
__global__ __launch_bounds__(256) void scan1_kernel(const int* __restrict__ cnt, int* __restrict__ ptr,
                                                    int* __restrict__ bsum, int N) {
    __shared__ int s[256];
    int tid = threadIdx.x;
    int base = blockIdx.x * 1024 + tid * 4;
    int c0 = (base + 0 < N) ? cnt[base + 0] : 0;
    int c1 = (base + 1 < N) ? cnt[base + 1] : 0;
    int c2 = (base + 2 < N) ? cnt[base + 2] : 0;
    int c3 = (base + 3 < N) ? cnt[base + 3] : 0;
    int tsum = c0 + c1 + c2 + c3;
    s[tid] = tsum;
    __syncthreads();
    for (int off = 1; off < 256; off <<= 1) {
        int t = (tid >= off) ? s[tid - off] : 0;
        __syncthreads();
        s[tid] += t;
        __syncthreads();
    }
    int excl = s[tid] - tsum;
    if (base + 0 < N) ptr[base + 0] = excl;
    if (base + 1 < N) ptr[base + 1] = excl + c0;
    if (base + 2 < N) ptr[base + 2] = excl + c0 + c1;
    if (base + 3 < N) ptr[base + 3] = excl + c0 + c1 + c2;
    if (tid == 255) bsum[blockIdx.x] = s[255];
}

__global__ __launch_bounds__(256) void scan2_kernel(const int* __restrict__ bsum, int* __restrict__ bscan, int nb) {
    __shared__ int s[256];
    int tid = threadIdx.x;
    int v = (tid < nb) ? bsum[tid] : 0;
    s[tid] = v;
    __syncthreads();
    for (int off = 1; off < 256; off <<= 1) {
        int t = (tid >= off) ? s[tid - off] : 0;
        __syncthreads();
        s[tid] += t;
        __syncthreads();
    }
    if (tid < nb) bscan[tid] = s[tid] - v;
}

// ptr += block prefix; cursor = ptr
__global__ __launch_bounds__(256) void scan3_kernel(int* __restrict__ ptr, const int* __restrict__ bscan,
                                                    int* __restrict__ cursor, int N) {
    int i = blockIdx.x * 256 + threadIdx.x;
    if (i < N) {
        int p = ptr[i] + bscan[i >> 10];
        ptr[i] = p;
        cursor[i] = p;
    }
}

// scatter edges into CSR slots: csr[slot] = (src, w) with w computed inline
__global__ __launch_bounds__(256) void fill_kernel(const int* __restrict__ ei,
                                                   const float* __restrict__ ea,
                                                   int* __restrict__ cursor,
                                                   int2* __restrict__ csr, int E, int N) {
    int e = blockIdx.x * 256 + threadIdx.x;
    if (e >= E) return;
    int s = ei[e];
    int d = ei[E + e];
    if ((unsigned)s >= (unsigned)N || (unsigned)d >= (unsigned)N) return;  // defensive
    const float4* a = (const float4*)(ea + (size_t)e * 8);
    float4 a0 = a[0], a1 = a[1];
    float wv = (a0.x + a0.y + a0.z + a0.w + a1.x + a1.y + a1.z + a1.w) * 0.125f;
    int slot = atomicAdd(&cursor[d], 1);
    csr[slot] = make_int2(s, __float_as_int(wv));
}

// atomic-free degree: walk own CSR row. deg = 1 (self-loop) + sum w.
__global__ __launch_bounds__(256) void degk_kernel(const int* __restrict__ ptr, const int* __restrict__ cnt,
                                                   const int2* __restrict__ csr,
                                                   float* __restrict__ dinv, int N) {
    int i = blockIdx.x * 256 + threadIdx.x;
    if (i >= N) return;
    int p = ptr[i], c = cnt[i];
    float deg = 1.0f;
    for (int j = 0; j < c; ++j) deg += __int_as_float(csr[p + j].y);
    dinv[i] = rsqrtf(deg);
}

// ---------------- g0 = dinv ⊙ (x @ W)  (256 -> 64) ----------------
// 1024-thread block; one 64KB W-stage serves 16 waves. Each lane accumulates
// 4 rows x 4 cols (wave covers 16 rows): LDS reads per k4 feed 64 FMAs.
#define ACC4(A, XV) \
    A.x = fmaf(XV.x, w0.x, A.x); A.y = fmaf(XV.x, w0.y, A.y); A.z = fmaf(XV.x, w0.z, A.z); A.w = fmaf(XV.x, w0.w, A.w); \
    A.x = fmaf(XV.y, w1.x, A.x); A.y = fmaf(XV.y, w1.y, A.y); A.z = fmaf(XV.y, w1.z, A.z); A.w = fmaf(XV.y, w1.w, A.w); \
    A.x = fmaf(XV.z, w2.x, A.x); A.y = fmaf(XV.z, w2.y, A.y); A.z = fmaf(XV.z, w2.z, A.z); A.w = fmaf(XV.z, w2.w, A.w); \
    A.x = fmaf(XV.w, w3.x, A.x); A.y = fmaf(XV.w, w3.y, A.y); A.z = fmaf(XV.w, w3.z, A.z); A.w = fmaf(XV.w, w3.w, A.w);

__global__ __launch_bounds__(1024) void xw_kernel(const float* __restrict__ x, const float* __restrict__ W,
                                                  const float* __restrict__ dinv,
                                                  float* __restrict__ y, int N) {
    __shared__ float Wl[F_IN * F_OUT];  // 64 KB
    const float4* W4 = (const float4*)W;
    float4* Wl4 = (float4*)Wl;
    for (int i = threadIdx.x; i < F_IN * F_OUT / 4; i += 1024) Wl4[i] = W4[i];
    __syncthreads();

    int gwave = (blockIdx.x * 1024 + threadIdx.x) >> 6;
    int nwaves = (gridDim.x * 1024) >> 6;
    int lane = threadIdx.x & 63;
    int r = lane >> 4;       // 0..3 -> which 4-row quad
    int jg = lane & 15;      // col group (4 cols)
    int ngroups = (N + 15) >> 4;

    for (int g = gwave; g < ngroups; g += nwaves) {
        int row0 = g * 16 + r * 4;  // this lane's rows: row0..row0+3
        float4 a0 = {0,0,0,0}, a1 = {0,0,0,0}, a2 = {0,0,0,0}, a3 = {0,0,0,0};
        if (row0 + 3 < N) {
            const float4* xr0 = (const float4*)(x + (size_t)(row0 + 0) * F_IN);
            const float4* xr1 = (const float4*)(x + (size_t)(row0 + 1) * F_IN);
            const float4* xr2 = (const float4*)(x + (size_t)(row0 + 2) * F_IN);
            const float4* xr3 = (const float4*)(x + (size_t)(row0 + 3) * F_IN);
#pragma unroll 2
            for (int k4 = 0; k4 < F_IN / 4; ++k4) {
                float4 xv0 = xr0[k4];
                float4 xv1 = xr1[k4];
                float4 xv2 = xr2[k4];
                float4 xv3 = xr3[k4];
                float4 w0 = Wl4[(k4 * 4 + 0) * 16 + jg];
                float4 w1 = Wl4[(k4 * 4 + 1) * 16 + jg];
                float4 w2 = Wl4[(k4 * 4 + 2) * 16 + jg];
                float4 w3 = Wl4[(k4 * 4 + 3) * 16 + jg];
                ACC4(a0, xv0)
                ACC4(a1, xv1)
                ACC4(a2, xv2)
                ACC4(a3, xv3)
            }
            float d0 = dinv[row0 + 0], d1 = dinv[row0 + 1], d2 = dinv[row0 + 2], d3 = dinv[row0 + 3];
            a0.x *= d0; a0.y *= d0; a0.z *= d0; a0.w *= d0;
            a1.x *= d1; a1.y *= d1; a1.z *= d1; a1.w *= d1;
            a2.x *= d2; a2.y *= d2; a2.z *= d2; a2.w *= d2;
            a3.x *= d3; a3.y *= d3; a3.z *= d3; a3.w *= d3;
            ((float4*)(y + (size_t)(row0 + 0) * F_OUT))[jg] = a0;
            ((float4*)(y + (size_t)(row0 + 1) * F_OUT))[jg] = a1;
            ((float4*)(y + (size_t)(row0 + 2) * F_OUT))[jg] = a2;
            ((float4*)(y + (size_t)(row0 + 3) * F_OUT))[jg] = a3;
        } else {
            // tail path (only when N % 16 != 0)
            for (int i4 = 0; i4 < 4; ++i4) {
                int row = row0 + i4;
                if (row >= N) break;
                const float4* xr = (const float4*)(x + (size_t)row * F_IN);
                float4 a = {0,0,0,0};
                for (int k4 = 0; k4 < F_IN / 4; ++k4) {
                    float4 xv = xr[k4];
                    float4 w0 = Wl4[(k4 * 4 + 0) * 16 + jg];
                    float4 w1 = Wl4[(k4 * 4 + 1) * 16 + jg];
                    float4 w2 = Wl4[(k4 * 4 + 2) * 16 + jg];
                    float4 w3 = Wl4[(k4 * 4 + 3) * 16 + jg];
                    ACC4(a, xv)
                }
                float di = dinv[row];
                a.x *= di; a.y *= di; a.z *= di; a.w *= di;
                ((float4*)(y + (size_t)row * F_OUT))[jg] = a;
            }
        }
    }
}

// ---------------- propagation in g-space: one wave per node, lane = feature ----------------
// g_out[d] = dinv[d]^2 * ( sum_e w_e * g_in[src] + g_in[d] )
__global__ __launch_bounds__(256) void prop_kernel(const float* __restrict__ gin, float* __restrict__ gout,
                                                   const int* __restrict__ ptr, const int* __restrict__ cnt,
                                                   const float* __restrict__ dinv,
                                                   const int2* __restrict__ csr, int N) {
    int node = blockIdx.x * 4 + (threadIdx.x >> 6);
    if (node >= N) return;
    int lane = threadIdx.x & 63;
    float acc = gin[(size_t)node * 64 + lane];  // self-loop, weight 1
    int p = ptr[node], c = cnt[node];
    int i = 0;
    for (; i + 8 <= c; i += 8) {
        int2 e0 = csr[p + i + 0];
        int2 e1 = csr[p + i + 1];
        int2 e2 = csr[p + i + 2];
        int2 e3 = csr[p + i + 3];
        int2 e4 = csr[p + i + 4];
        int2 e5 = csr[p + i + 5];
        int2 e6 = csr[p + i + 6];
        int2 e7 = csr[p + i + 7];
        float v0 = gin[(size_t)e0.x * 64 + lane];
        float v1 = gin[(size_t)e1.x * 64 + lane];
        float v2 = gin[(size_t)e2.x * 64 + lane];
        float v3 = gin[(size_t)e3.x * 64 + lane];
        float v4 = gin[(size_t)e4.x * 64 + lane];
        float v5 = gin[(size_t)e5.x * 64 + lane];
        float v6 = gin[(size_t)e6.x * 64 + lane];
        float v7 = gin[(size_t)e7.x * 64 + lane];
        acc = fmaf(__int_as_float(e0.y), v0, acc);
        acc = fmaf(__int_as_float(e1.y), v1, acc);
        acc = fmaf(__int_as_float(e2.y), v2, acc);
        acc = fmaf(__int_as_float(e3.y), v3, acc);
        acc = fmaf(__int_as_float(e4.y), v4, acc);
        acc = fmaf(__int_as_float(e5.y), v5, acc);
        acc = fmaf(__int_as_float(e6.y), v6, acc);
        acc = fmaf(__int_as_float(e7.y), v7, acc);
    }
    for (; i < c; ++i) {
        int2 e = csr[p + i];
        acc = fmaf(__int_as_float(e.y), gin[(size_t)e.x * 64 + lane], acc);
    }
    float di = dinv[node];
    gout[(size_t)node * 64 + lane] = acc * di * di;
}

// ---------------- hop 3 fused with epilogue ----------------
// logits = acc * dinv[d]  (= g3/dinv);  out = log_softmax(relu(logits + b))
__global__ __launch_bounds__(256) void prop_final_kernel(const float* __restrict__ gin, float* __restrict__ out,
                                                         const int* __restrict__ ptr, const int* __restrict__ cnt,
                                                         const float* __restrict__ dinv,
                                                         const int2* __restrict__ csr,
                                                         const float* __restrict__ b, int N) {
    int node = blockIdx.x * 4 + (threadIdx.x >> 6);
    if (node >= N) return;
    int lane = threadIdx.x & 63;
    float acc = gin[(size_t)node * 64 + lane];
    int p = ptr[node], c = cnt[node];
    int i = 0;
    for (; i + 8 <= c; i += 8) {
        int2 e0 = csr[p + i + 0];
        int2 e1 = csr[p + i + 1];
        int2 e2 = csr[p + i + 2];
        int2 e3 = csr[p + i + 3];
        int2 e4 = csr[p + i + 4];
        int2 e5 = csr[p + i + 5];
        int2 e6 = csr[p + i + 6];
        int2 e7 = csr[p + i + 7];
        float v0 = gin[(size_t)e0.x * 64 + lane];
        float v1 = gin[(size_t)e1.x * 64 + lane];
        float v2 = gin[(size_t)e2.x * 64 + lane];
        float v3 = gin[(size_t)e3.x * 64 + lane];
        float v4 = gin[(size_t)e4.x * 64 + lane];
        float v5 = gin[(size_t)e5.x * 64 + lane];
        float v6 = gin[(size_t)e6.x * 64 + lane];
        float v7 = gin[(size_t)e7.x * 64 + lane];
        acc = fmaf(__int_as_float(e0.y), v0, acc);
        acc = fmaf(__int_as_float(e1.y), v1, acc);
        acc = fmaf(__int_as_float(e2.y), v2, acc);
        acc = fmaf(__int_as_float(e3.y), v3, acc);
        acc = fmaf(__int_as_float(e4.y), v4, acc);
        acc = fmaf(__int_as_float(e5.y), v5, acc);
        acc = fmaf(__int_as_float(e6.y), v6, acc);
        acc = fmaf(__int_as_float(e7.y), v7, acc);
    }
    for (; i < c; ++i) {
        int2 e = csr[p + i];
        acc = fmaf(__int_as_float(e.y), gin[(size_t)e.x * 64 + lane], acc);
    }
    float v = acc * dinv[node] + b[lane];   // h3 = g3/dinv = (acc*di^2)/di = acc*di
    v = fmaxf(v, 0.0f);
    float m = v;
    for (int off = 32; off; off >>= 1) m = fmaxf(m, __shfl_xor(m, off, 64));
    float ex = expf(v - m);
    float s = ex;
    for (int off = 32; off; off >>= 1) s += __shfl_xor(s, off, 64);
    out[(size_t)node * 64 + lane] = (v - m) - logf(s);
}

// ---------------- launch ----------------

extern "C" void kernel_launch(void* const* d_in, const int* in_sizes, int n_in,
                              void* d_out, int out_size, void* d_ws, size_t ws_size,
                              hipStream_t stream) {
    const float* x = (const float*)d_in[0];
    const float* edge_attr = (const float*)d_in[1];
    const float* W = (const float*)d_in[2];
    const float* b = (const float*)d_in[3];
    const int* ei = (const int*)d_in[4];   // harness delivers integer inputs as int32
    int N = in_sizes[0] / F_IN;
    int E = in_sizes[4] / 2;
    float* out = (float*)d_out;

    char* ws = (char*)d_ws;
    size_t off = 0;
    auto alloc = [&](size_t bytes) -> char* {
        char* p = ws + off;
        off += (bytes + 255) & ~(size_t)255;
        return p;
    };
    float* dinv    = (float*)alloc((size_t)N * 4);
    int*   cnt     = (int*)alloc((size_t)N * 4);
    int*   ptr     = (int*)alloc((size_t)N * 4);
    int*   cursor  = (int*)alloc((size_t)N * 4);
    int*   bsum    = (int*)alloc(256 * 4);
    int*   bscan   = (int*)alloc(256 * 4);
    int2*  csr     = (int2*)alloc((size_t)E * 8);
    float* h0      = (float*)alloc((size_t)N * 64 * 4);
    float* h1      = (float*)alloc((size_t)N * 64 * 4);
    // total ~65 MB of ws

    int nbN = (N + 255) / 256;
    int nbE = (E + 255) / 256;
    int nb1024 = (N + 1023) / 1024;
    int nbNode4 = (N + 3) / 4;

    init_kernel<<<nbN, 256, 0, stream>>>(cnt, N);
    hist_kernel<<<nbE, 256, 0, stream>>>(ei + E, E, N, cnt);
    scan1_kernel<<<nb1024, 256, 0, stream>>>(cnt, ptr, bsum, N);
    scan2_kernel<<<1, 256, 0, stream>>>(bsum, bscan, nb1024);
    scan3_kernel<<<nbN, 256, 0, stream>>>(ptr, bscan, cursor, N);
    fill_kernel<<<nbE, 256, 0, stream>>>(ei, edge_attr, cursor, csr, E, N);
    degk_kernel<<<nbN, 256, 0, stream>>>(ptr, cnt, csr, dinv, N);

    xw_kernel<<<256, 1024, 0, stream>>>(x, W, dinv, h0, N);

    // hops 1,2 ping-pong; hop 3 fused with epilogue writes d_out
    prop_kernel<<<nbNode4, 256, 0, stream>>>(h0, h1, ptr, cnt, dinv, csr, N);
    prop_kernel<<<nbNode4, 256, 0, stream>>>(h1, h0, ptr, cnt, dinv, csr, N);
    prop_final_kernel<<<nbNode4, 256, 0, stream>>>(h0, out, ptr, cnt, dinv, csr, b, N);
}

// Round 9
// 610.613 us; speedup vs baseline: 1.2015x; 1.0512x over previous
//
#include <hip/hip_runtime.h>
#include <hip/hip_bf16.h>

// SGC: out = log_softmax(relu(A_hat^3 (x W) + b))
// A_hat = D^-1/2 (A + I) D^-1/2 with edge weights = mean(edge_attr, axis=1)
//
// Structure:
//  - project x@W (256->64) BEFORE the 3 hops (linearity) -> 4x less gather traffic
//  - propagate in scaled space g = D^-1/2 h:
//        g_{k+1}[d] = dinv[d]^2 * ( sum_e w_e * g_k[src] + g_k[d] ),  h_3 = g_3 / dinv
//    => CSR stores raw (src, w); deg computed atomic-free from the finished CSR.
//  - deterministic two-pass CSR build: pass1 does the ONLY atomic pass
//    (seq[e] = atomicAdd(cnt[dst])), pass2 scatters with zero atomics.
//  - xw: register-blocked 4x4 per lane, 1024-thread blocks, grid 512 -> 2 blocks/CU
//    (launch_bounds(1024,8), VGPR<=64; no hand prefetch -> no spill risk).
//  - hop 3 fused with bias+relu+log_softmax epilogue (h3 = acc*dinv).

#define F_IN 256
#define F_OUT 64

// ---------------- prep kernels ----------------

__global__ __launch_bounds__(256) void init_kernel(int* __restrict__ cnt, int N) {
    int i = blockIdx.x * 256 + threadIdx.x;
    if (i < N) cnt[i] = 0;
}

// pass 1: w[e] = mean(edge_attr[e]); seq[e] = slot of edge e within dst row
// (single atomic pass; 51MB edge_attr streamed exactly once)
__global__ __launch_bounds__(256) void pass1_kernel(const float* __restrict__ ea,
                                                    const int* __restrict__ ei_dst,
                                                    int E, int N,
                                                    float* __restrict__ w,
                                                    int* __restrict__ seq,
                                                    int* __restrict__ cnt) {
    int e = blockIdx.x * 256 + threadIdx.x;
    if (e >= E) return;
    const float4* a = (const float4*)(ea + (size_t)e * 8);
    float4 a0 = a[0], a1 = a[1];
    float wv = (a0.x + a0.y + a0.z + a0.w + a1.x + a1.y + a1.z + a1.w) * 0.125f;
    w[e] = wv;
    int d = ei_dst[e];
    if ((unsigned)d >= (unsigned)N) { seq[e] = -1; return; }  // defensive
    seq[e] = atomicAdd(&cnt[d], 1);
}

// 3-phase exclusive scan of cnt -> ptr (1024 elements per block)
__global__ __launch_bounds__(256) void scan1_kernel(const int* __restrict__ cnt, int* __restrict__ ptr,
                                                    int* __restrict__ bsum, int N) {
    __shared__ int s[256];
    int tid = threadIdx.x;
    int base = blockIdx.x * 1024 + tid * 4;
    int c0 = (base + 0 < N) ? cnt[base + 0] : 0;
    int c1 = (base + 1 < N) ? cnt[base + 1] : 0;
    int c2 = (base + 2 < N) ? cnt[base + 2] : 0;
    int c3 = (base + 3 < N) ? cnt[base + 3] : 0;
    int tsum = c0 + c1 + c2 + c3;
    s[tid] = tsum;
    __syncthreads();
    for (int off = 1; off < 256; off <<= 1) {
        int t = (tid >= off) ? s[tid - off] : 0;
        __syncthreads();
        s[tid] += t;
        __syncthreads();
    }
    int excl = s[tid] - tsum;
    if (base + 0 < N) ptr[base + 0] = excl;
    if (base + 1 < N) ptr[base + 1] = excl + c0;
    if (base + 2 < N) ptr[base + 2] = excl + c0 + c1;
    if (base + 3 < N) ptr[base + 3] = excl + c0 + c1 + c2;
    if (tid == 255) bsum[blockIdx.x] = s[255];
}

__global__ __launch_bounds__(256) void scan2_kernel(const int* __restrict__ bsum, int* __restrict__ bscan, int nb) {
    __shared__ int s[256];
    int tid = threadIdx.x;
    int v = (tid < nb) ? bsum[tid] : 0;
    s[tid] = v;
    __syncthreads();
    for (int off = 1; off < 256; off <<= 1) {
        int t = (tid >= off) ? s[tid - off] : 0;
        __syncthreads();
        s[tid] += t;
        __syncthreads();
    }
    if (tid < nb) bscan[tid] = s[tid] - v;
}

// ptr += block prefix
__global__ __launch_bounds__(256) void scan3_kernel(int* __restrict__ ptr, const int* __restrict__ bscan, int N) {
    int i = blockIdx.x * 256 + threadIdx.x;
    if (i < N) ptr[i] += bscan[i >> 10];
}

// pass 2: deterministic scatter, zero atomics: csr[ptr[d]+seq[e]] = (src, w)
__global__ __launch_bounds__(256) void pass2_kernel(const int* __restrict__ ei,
                                                    const float* __restrict__ w,
                                                    const int* __restrict__ seq,
                                                    const int* __restrict__ ptr,
                                                    int2* __restrict__ csr, int E, int N) {
    int e = blockIdx.x * 256 + threadIdx.x;
    if (e >= E) return;
    int s = ei[e];
    int d = ei[E + e];
    int q = seq[e];
    if ((unsigned)s >= (unsigned)N || (unsigned)d >= (unsigned)N || q < 0) return;  // defensive
    csr[ptr[d] + q] = make_int2(s, __float_as_int(w[e]));
}

// atomic-free degree: walk own CSR row. deg = 1 (self-loop) + sum w.
__global__ __launch_bounds__(256) void degk_kernel(const int* __restrict__ ptr, const int* __restrict__ cnt,
                                                   const int2* __restrict__ csr,
                                                   float* __restrict__ dinv, int N) {
    int i = blockIdx.x * 256 + threadIdx.x;
    if (i >= N) return;
    int p = ptr[i], c = cnt[i];
    float deg = 1.0f;
    for (int j = 0; j < c; ++j) deg += __int_as_float(csr[p + j].y);
    dinv[i] = rsqrtf(deg);
}

// ---------------- g0 = dinv ⊙ (x @ W)  (256 -> 64) ----------------
// 1024-thread block; one 64KB W-stage serves 16 waves; launch_bounds(1024,8)
// forces VGPR<=64 so 2 blocks (32 waves) co-reside per CU (R5 measured VGPR=40;
// the old occupancy ceiling was grid=256 = 1 block/CU, fixed via grid=512).
#define ACC4(A, XV) \
    A.x = fmaf(XV.x, w0.x, A.x); A.y = fmaf(XV.x, w0.y, A.y); A.z = fmaf(XV.x, w0.z, A.z); A.w = fmaf(XV.x, w0.w, A.w); \
    A.x = fmaf(XV.y, w1.x, A.x); A.y = fmaf(XV.y, w1.y, A.y); A.z = fmaf(XV.y, w1.z, A.z); A.w = fmaf(XV.y, w1.w, A.w); \
    A.x = fmaf(XV.z, w2.x, A.x); A.y = fmaf(XV.z, w2.y, A.y); A.z = fmaf(XV.z, w2.z, A.z); A.w = fmaf(XV.z, w2.w, A.w); \
    A.x = fmaf(XV.w, w3.x, A.x); A.y = fmaf(XV.w, w3.y, A.y); A.z = fmaf(XV.w, w3.z, A.z); A.w = fmaf(XV.w, w3.w, A.w);

__global__ __launch_bounds__(1024, 8) void xw_kernel(const float* __restrict__ x, const float* __restrict__ W,
                                                     const float* __restrict__ dinv,
                                                     float* __restrict__ y, int N) {
    __shared__ float Wl[F_IN * F_OUT];  // 64 KB
    const float4* W4 = (const float4*)W;
    float4* Wl4 = (float4*)Wl;
    for (int i = threadIdx.x; i < F_IN * F_OUT / 4; i += 1024) Wl4[i] = W4[i];
    __syncthreads();

    int gwave = (blockIdx.x * 1024 + threadIdx.x) >> 6;
    int nwaves = (gridDim.x * 1024) >> 6;
    int lane = threadIdx.x & 63;
    int r = lane >> 4;       // 0..3 -> which 4-row quad
    int jg = lane & 15;      // col group (4 cols)
    int ngroups = (N + 15) >> 4;

    for (int g = gwave; g < ngroups; g += nwaves) {
        int row0 = g * 16 + r * 4;  // this lane's rows: row0..row0+3
        float4 a0 = {0,0,0,0}, a1 = {0,0,0,0}, a2 = {0,0,0,0}, a3 = {0,0,0,0};
        if (row0 + 3 < N) {
            const float4* xr0 = (const float4*)(x + (size_t)(row0 + 0) * F_IN);
            const float4* xr1 = (const float4*)(x + (size_t)(row0 + 1) * F_IN);
            const float4* xr2 = (const float4*)(x + (size_t)(row0 + 2) * F_IN);
            const float4* xr3 = (const float4*)(x + (size_t)(row0 + 3) * F_IN);
#pragma unroll 2
            for (int k4 = 0; k4 < F_IN / 4; ++k4) {
                float4 xv0 = xr0[k4];
                float4 xv1 = xr1[k4];
                float4 xv2 = xr2[k4];
                float4 xv3 = xr3[k4];
                float4 w0 = Wl4[(k4 * 4 + 0) * 16 + jg];
                float4 w1 = Wl4[(k4 * 4 + 1) * 16 + jg];
                float4 w2 = Wl4[(k4 * 4 + 2) * 16 + jg];
                float4 w3 = Wl4[(k4 * 4 + 3) * 16 + jg];
                ACC4(a0, xv0)
                ACC4(a1, xv1)
                ACC4(a2, xv2)
                ACC4(a3, xv3)
            }
            float d0 = dinv[row0 + 0], d1 = dinv[row0 + 1], d2 = dinv[row0 + 2], d3 = dinv[row0 + 3];
            a0.x *= d0; a0.y *= d0; a0.z *= d0; a0.w *= d0;
            a1.x *= d1; a1.y *= d1; a1.z *= d1; a1.w *= d1;
            a2.x *= d2; a2.y *= d2; a2.z *= d2; a2.w *= d2;
            a3.x *= d3; a3.y *= d3; a3.z *= d3; a3.w *= d3;
            ((float4*)(y + (size_t)(row0 + 0) * F_OUT))[jg] = a0;
            ((float4*)(y + (size_t)(row0 + 1) * F_OUT))[jg] = a1;
            ((float4*)(y + (size_t)(row0 + 2) * F_OUT))[jg] = a2;
            ((float4*)(y + (size_t)(row0 + 3) * F_OUT))[jg] = a3;
        } else {
            // tail path (only when N % 16 != 0)
            for (int i4 = 0; i4 < 4; ++i4) {
                int row = row0 + i4;
                if (row >= N) break;
                const float4* xr = (const float4*)(x + (size_t)row * F_IN);
                float4 a = {0,0,0,0};
                for (int k4 = 0; k4 < F_IN / 4; ++k4) {
                    float4 xv = xr[k4];
                    float4 w0 = Wl4[(k4 * 4 + 0) * 16 + jg];
                    float4 w1 = Wl4[(k4 * 4 + 1) * 16 + jg];
                    float4 w2 = Wl4[(k4 * 4 + 2) * 16 + jg];
                    float4 w3 = Wl4[(k4 * 4 + 3) * 16 + jg];
                    ACC4(a, xv)
                }
                float di = dinv[row];
                a.x *= di; a.y *= di; a.z *= di; a.w *= di;
                ((float4*)(y + (size_t)row * F_OUT))[jg] = a;
            }
        }
    }
}

// ---------------- propagation in g-space: one wave per node, lane = feature ----------------
// g_out[d] = dinv[d]^2 * ( sum_e w_e * g_in[src] + g_in[d] )
__global__ __launch_bounds__(256) void prop_kernel(const float* __restrict__ gin, float* __restrict__ gout,
                                                   const int* __restrict__ ptr, const int* __restrict__ cnt,
                                                   const float* __restrict__ dinv,
                                                   const int2* __restrict__ csr, int N) {
    int node = blockIdx.x * 4 + (threadIdx.x >> 6);
    if (node >= N) return;
    int lane = threadIdx.x & 63;
    float acc = gin[(size_t)node * 64 + lane];  // self-loop, weight 1
    int p = ptr[node], c = cnt[node];
    int i = 0;
    for (; i + 8 <= c; i += 8) {
        int2 e0 = csr[p + i + 0];
        int2 e1 = csr[p + i + 1];
        int2 e2 = csr[p + i + 2];
        int2 e3 = csr[p + i + 3];
        int2 e4 = csr[p + i + 4];
        int2 e5 = csr[p + i + 5];
        int2 e6 = csr[p + i + 6];
        int2 e7 = csr[p + i + 7];
        float v0 = gin[(size_t)e0.x * 64 + lane];
        float v1 = gin[(size_t)e1.x * 64 + lane];
        float v2 = gin[(size_t)e2.x * 64 + lane];
        float v3 = gin[(size_t)e3.x * 64 + lane];
        float v4 = gin[(size_t)e4.x * 64 + lane];
        float v5 = gin[(size_t)e5.x * 64 + lane];
        float v6 = gin[(size_t)e6.x * 64 + lane];
        float v7 = gin[(size_t)e7.x * 64 + lane];
        acc = fmaf(__int_as_float(e0.y), v0, acc);
        acc = fmaf(__int_as_float(e1.y), v1, acc);
        acc = fmaf(__int_as_float(e2.y), v2, acc);
        acc = fmaf(__int_as_float(e3.y), v3, acc);
        acc = fmaf(__int_as_float(e4.y), v4, acc);
        acc = fmaf(__int_as_float(e5.y), v5, acc);
        acc = fmaf(__int_as_float(e6.y), v6, acc);
        acc = fmaf(__int_as_float(e7.y), v7, acc);
    }
    for (; i < c; ++i) {
        int2 e = csr[p + i];
        acc = fmaf(__int_as_float(e.y), gin[(size_t)e.x * 64 + lane], acc);
    }
    float di = dinv[node];
    gout[(size_t)node * 64 + lane] = acc * di * di;
}

// ---------------- hop 3 fused with epilogue ----------------
// logits = acc * dinv[d]  (= g3/dinv);  out = log_softmax(relu(logits + b))
__global__ __launch_bounds__(256) void prop_final_kernel(const float* __restrict__ gin, float* __restrict__ out,
                                                         const int* __restrict__ ptr, const int* __restrict__ cnt,
                                                         const float* __restrict__ dinv,
                                                         const int2* __restrict__ csr,
                                                         const float* __restrict__ b, int N) {
    int node = blockIdx.x * 4 + (threadIdx.x >> 6);
    if (node >= N) return;
    int lane = threadIdx.x & 63;
    float acc = gin[(size_t)node * 64 + lane];
    int p = ptr[node], c = cnt[node];
    int i = 0;
    for (; i + 8 <= c; i += 8) {
        int2 e0 = csr[p + i + 0];
        int2 e1 = csr[p + i + 1];
        int2 e2 = csr[p + i + 2];
        int2 e3 = csr[p + i + 3];
        int2 e4 = csr[p + i + 4];
        int2 e5 = csr[p + i + 5];
        int2 e6 = csr[p + i + 6];
        int2 e7 = csr[p + i + 7];
        float v0 = gin[(size_t)e0.x * 64 + lane];
        float v1 = gin[(size_t)e1.x * 64 + lane];
        float v2 = gin[(size_t)e2.x * 64 + lane];
        float v3 = gin[(size_t)e3.x * 64 + lane];
        float v4 = gin[(size_t)e4.x * 64 + lane];
        float v5 = gin[(size_t)e5.x * 64 + lane];
        float v6 = gin[(size_t)e6.x * 64 + lane];
        float v7 = gin[(size_t)e7.x * 64 + lane];
        acc = fmaf(__int_as_float(e0.y), v0, acc);
        acc = fmaf(__int_as_float(e1.y), v1, acc);
        acc = fmaf(__int_as_float(e2.y), v2, acc);
        acc = fmaf(__int_as_float(e3.y), v3, acc);
        acc = fmaf(__int_as_float(e4.y), v4, acc);
        acc = fmaf(__int_as_float(e5.y), v5, acc);
        acc = fmaf(__int_as_float(e6.y), v6, acc);
        acc = fmaf(__int_as_float(e7.y), v7, acc);
    }
    for (; i < c; ++i) {
        int2 e = csr[p + i];
        acc = fmaf(__int_as_float(e.y), gin[(size_t)e.x * 64 + lane], acc);
    }
    float v = acc * dinv[node] + b[lane];   // h3 = g3/dinv = (acc*di^2)/di = acc*di
    v = fmaxf(v, 0.0f);
    float m = v;
    for (int off = 32; off; off >>= 1) m = fmaxf(m, __shfl_xor(m, off, 64));
    float ex = expf(v - m);
    float s = ex;
    for (int off = 32; off; off >>= 1) s += __shfl_xor(s, off, 64);
    out[(size_t)node * 64 + lane] = (v - m) - logf(s);
}

// ---------------- launch ----------------

extern "C" void kernel_launch(void* const* d_in, const int* in_sizes, int n_in,
                              void* d_out, int out_size, void* d_ws, size_t ws_size,
                              hipStream_t stream) {
    const float* x = (const float*)d_in[0];
    const float* edge_attr = (const float*)d_in[1];
    const float* W = (const float*)d_in[2];
    const float* b = (const float*)d_in[3];
    const int* ei = (const int*)d_in[4];   // harness delivers integer inputs as int32
    int N = in_sizes[0] / F_IN;
    int E = in_sizes[4] / 2;
    float* out = (float*)d_out;

    char* ws = (char*)d_ws;
    size_t off = 0;
    auto alloc = [&](size_t bytes) -> char* {
        char* p = ws + off;
        off += (bytes + 255) & ~(size_t)255;
        return p;
    };
    float* dinv    = (float*)alloc((size_t)N * 4);
    int*   cnt     = (int*)alloc((size_t)N * 4);
    int*   ptr     = (int*)alloc((size_t)N * 4);
    int*   bsum    = (int*)alloc(256 * 4);
    int*   bscan   = (int*)alloc(256 * 4);
    float* w       = (float*)alloc((size_t)E * 4);
    int*   seq     = (int*)alloc((size_t)E * 4);
    int2*  csr     = (int2*)alloc((size_t)E * 8);
    float* h0      = (float*)alloc((size_t)N * 64 * 4);
    float* h1      = (float*)alloc((size_t)N * 64 * 4);
    // total ~77 MB of ws

    int nbN = (N + 255) / 256;
    int nbE = (E + 255) / 256;
    int nb1024 = (N + 1023) / 1024;
    int nbNode4 = (N + 3) / 4;

    init_kernel<<<nbN, 256, 0, stream>>>(cnt, N);
    pass1_kernel<<<nbE, 256, 0, stream>>>(edge_attr, ei + E, E, N, w, seq, cnt);
    scan1_kernel<<<nb1024, 256, 0, stream>>>(cnt, ptr, bsum, N);
    scan2_kernel<<<1, 256, 0, stream>>>(bsum, bscan, nb1024);
    scan3_kernel<<<nbN, 256, 0, stream>>>(ptr, bscan, N);
    pass2_kernel<<<nbE, 256, 0, stream>>>(ei, w, seq, ptr, csr, E, N);
    degk_kernel<<<nbN, 256, 0, stream>>>(ptr, cnt, csr, dinv, N);

    xw_kernel<<<512, 1024, 0, stream>>>(x, W, dinv, h0, N);

    // hops 1,2 ping-pong; hop 3 fused with epilogue writes d_out
    prop_kernel<<<nbNode4, 256, 0, stream>>>(h0, h1, ptr, cnt, dinv, csr, N);
    prop_kernel<<<nbNode4, 256, 0, stream>>>(h1, h0, ptr, cnt, dinv, csr, N);
    prop_final_kernel<<<nbNode4, 256, 0, stream>>>(h0, out, ptr, cnt, dinv, csr, b, N);
}

// Round 11
// 595.897 us; speedup vs baseline: 1.2312x; 1.0247x over previous
//
#include <hip/hip_runtime.h>
#include <hip/hip_bf16.h>

// SGC: out = log_softmax(relu(A_hat^3 (x W) + b))
// A_hat = D^-1/2 (A + I) D^-1/2 with edge weights = mean(edge_attr, axis=1)
//
// Structure:
//  - project x@W (256->64) BEFORE the 3 hops (linearity) -> 4x less gather traffic
//  - propagate in scaled space g = D^-1/2 h:
//        g_{k+1}[d] = dinv[d]^2 * ( sum_e w_e * g_k[src] + g_k[d] ),  h_3 = g_3 / dinv
//    => CSR stores raw (src, w); deg computed atomic-free from the finished CSR.
//  - deterministic two-pass CSR build: pass1 does the ONLY atomic pass
//    (seq[e] = atomicAdd(cnt[dst])), pass2 scatters with zero atomics.
//  - xw: 512-thread blocks, launch_bounds(512,4) -> VGPR cap 128 (R9 lesson:
//    (1024,8) squeezed VGPR to 32 and killed ILP; VALUBusy 21%). 2 blocks/CU
//    (128KB LDS), 16 waves/CU, k+1 software prefetch of x (~76 VGPR, no spill).
//  - hop 3 fused with bias+relu+log_softmax epilogue (h3 = acc*dinv).

#define F_IN 256
#define F_OUT 64

// ---------------- prep kernels ----------------

__global__ __launch_bounds__(256) void init_kernel(int* __restrict__ cnt, int N) {
    int i = blockIdx.x * 256 + threadIdx.x;
    if (i < N) cnt[i] = 0;
}

// pass 1: w[e] = mean(edge_attr[e]); seq[e] = slot of edge e within dst row
// (single atomic pass; 51MB edge_attr streamed exactly once)
__global__ __launch_bounds__(256) void pass1_kernel(const float* __restrict__ ea,
                                                    const int* __restrict__ ei_dst,
                                                    int E, int N,
                                                    float* __restrict__ w,
                                                    int* __restrict__ seq,
                                                    int* __restrict__ cnt) {
    int e = blockIdx.x * 256 + threadIdx.x;
    if (e >= E) return;
    const float4* a = (const float4*)(ea + (size_t)e * 8);
    float4 a0 = a[0], a1 = a[1];
    float wv = (a0.x + a0.y + a0.z + a0.w + a1.x + a1.y + a1.z + a1.w) * 0.125f;
    w[e] = wv;
    int d = ei_dst[e];
    if ((unsigned)d >= (unsigned)N) { seq[e] = -1; return; }  // defensive
    seq[e] = atomicAdd(&cnt[d], 1);
}

// 3-phase exclusive scan of cnt -> ptr (1024 elements per block)
__global__ __launch_bounds__(256) void scan1_kernel(const int* __restrict__ cnt, int* __restrict__ ptr,
                                                    int* __restrict__ bsum, int N) {
    __shared__ int s[256];
    int tid = threadIdx.x;
    int base = blockIdx.x * 1024 + tid * 4;
    int c0 = (base + 0 < N) ? cnt[base + 0] : 0;
    int c1 = (base + 1 < N) ? cnt[base + 1] : 0;
    int c2 = (base + 2 < N) ? cnt[base + 2] : 0;
    int c3 = (base + 3 < N) ? cnt[base + 3] : 0;
    int tsum = c0 + c1 + c2 + c3;
    s[tid] = tsum;
    __syncthreads();
    for (int off = 1; off < 256; off <<= 1) {
        int t = (tid >= off) ? s[tid - off] : 0;
        __syncthreads();
        s[tid] += t;
        __syncthreads();
    }
    int excl = s[tid] - tsum;
    if (base + 0 < N) ptr[base + 0] = excl;
    if (base + 1 < N) ptr[base + 1] = excl + c0;
    if (base + 2 < N) ptr[base + 2] = excl + c0 + c1;
    if (base + 3 < N) ptr[base + 3] = excl + c0 + c1 + c2;
    if (tid == 255) bsum[blockIdx.x] = s[255];
}

__global__ __launch_bounds__(256) void scan2_kernel(const int* __restrict__ bsum, int* __restrict__ bscan, int nb) {
    __shared__ int s[256];
    int tid = threadIdx.x;
    int v = (tid < nb) ? bsum[tid] : 0;
    s[tid] = v;
    __syncthreads();
    for (int off = 1; off < 256; off <<= 1) {
        int t = (tid >= off) ? s[tid - off] : 0;
        __syncthreads();
        s[tid] += t;
        __syncthreads();
    }
    if (tid < nb) bscan[tid] = s[tid] - v;
}

// ptr += block prefix
__global__ __launch_bounds__(256) void scan3_kernel(int* __restrict__ ptr, const int* __restrict__ bscan, int N) {
    int i = blockIdx.x * 256 + threadIdx.x;
    if (i < N) ptr[i] += bscan[i >> 10];
}

// pass 2: deterministic scatter, zero atomics: csr[ptr[d]+seq[e]] = (src, w)
__global__ __launch_bounds__(256) void pass2_kernel(const int* __restrict__ ei,
                                                    const float* __restrict__ w,
                                                    const int* __restrict__ seq,
                                                    const int* __restrict__ ptr,
                                                    int2* __restrict__ csr, int E, int N) {
    int e = blockIdx.x * 256 + threadIdx.x;
    if (e >= E) return;
    int s = ei[e];
    int d = ei[E + e];
    int q = seq[e];
    if ((unsigned)s >= (unsigned)N || (unsigned)d >= (unsigned)N || q < 0) return;  // defensive
    csr[ptr[d] + q] = make_int2(s, __float_as_int(w[e]));
}

// atomic-free degree: walk own CSR row. deg = 1 (self-loop) + sum w.
__global__ __launch_bounds__(256) void degk_kernel(const int* __restrict__ ptr, const int* __restrict__ cnt,
                                                   const int2* __restrict__ csr,
                                                   float* __restrict__ dinv, int N) {
    int i = blockIdx.x * 256 + threadIdx.x;
    if (i >= N) return;
    int p = ptr[i], c = cnt[i];
    float deg = 1.0f;
    for (int j = 0; j < c; ++j) deg += __int_as_float(csr[p + j].y);
    dinv[i] = rsqrtf(deg);
}

// ---------------- g0 = dinv ⊙ (x @ W)  (256 -> 64) ----------------
// 512-thread block (8 waves); one 64KB W-stage serves 8 waves; 2 blocks/CU.
// launch_bounds(512,4) -> VGPR cap 128: room for 4x4 register block + k+1
// software prefetch (~76 VGPR). Grid = ceil(ngroups/8) = one 16-row group/wave.
#define ACC4(A, XV) \
    A.x = fmaf(XV.x, w0.x, A.x); A.y = fmaf(XV.x, w0.y, A.y); A.z = fmaf(XV.x, w0.z, A.z); A.w = fmaf(XV.x, w0.w, A.w); \
    A.x = fmaf(XV.y, w1.x, A.x); A.y = fmaf(XV.y, w1.y, A.y); A.z = fmaf(XV.y, w1.z, A.z); A.w = fmaf(XV.y, w1.w, A.w); \
    A.x = fmaf(XV.z, w2.x, A.x); A.y = fmaf(XV.z, w2.y, A.y); A.z = fmaf(XV.z, w2.z, A.z); A.w = fmaf(XV.z, w2.w, A.w); \
    A.x = fmaf(XV.w, w3.x, A.x); A.y = fmaf(XV.w, w3.y, A.y); A.z = fmaf(XV.w, w3.z, A.z); A.w = fmaf(XV.w, w3.w, A.w);

__global__ __launch_bounds__(512, 4) void xw_kernel(const float* __restrict__ x, const float* __restrict__ W,
                                                    const float* __restrict__ dinv,
                                                    float* __restrict__ y, int N) {
    __shared__ float Wl[F_IN * F_OUT];  // 64 KB
    const float4* W4 = (const float4*)W;
    float4* Wl4 = (float4*)Wl;
    for (int i = threadIdx.x; i < F_IN * F_OUT / 4; i += 512) Wl4[i] = W4[i];
    __syncthreads();

    int gwave = (blockIdx.x * 512 + threadIdx.x) >> 6;
    int nwaves = (gridDim.x * 512) >> 6;
    int lane = threadIdx.x & 63;
    int r = lane >> 4;       // 0..3 -> which 4-row quad
    int jg = lane & 15;      // col group (4 cols)
    int ngroups = (N + 15) >> 4;

    for (int g = gwave; g < ngroups; g += nwaves) {
        int row0 = g * 16 + r * 4;  // this lane's rows: row0..row0+3
        float4 a0 = {0,0,0,0}, a1 = {0,0,0,0}, a2 = {0,0,0,0}, a3 = {0,0,0,0};
        if (row0 + 3 < N) {
            const float4* xr0 = (const float4*)(x + (size_t)(row0 + 0) * F_IN);
            const float4* xr1 = (const float4*)(x + (size_t)(row0 + 1) * F_IN);
            const float4* xr2 = (const float4*)(x + (size_t)(row0 + 2) * F_IN);
            const float4* xr3 = (const float4*)(x + (size_t)(row0 + 3) * F_IN);
            float4 xv0 = xr0[0], xv1 = xr1[0], xv2 = xr2[0], xv3 = xr3[0];
#pragma unroll 2
            for (int k4 = 0; k4 < F_IN / 4; ++k4) {
                int kn = (k4 + 1) & (F_IN / 4 - 1);   // wrap: last iter re-reads k=0 (discarded)
                float4 nx0 = xr0[kn];
                float4 nx1 = xr1[kn];
                float4 nx2 = xr2[kn];
                float4 nx3 = xr3[kn];
                float4 w0 = Wl4[(k4 * 4 + 0) * 16 + jg];
                float4 w1 = Wl4[(k4 * 4 + 1) * 16 + jg];
                float4 w2 = Wl4[(k4 * 4 + 2) * 16 + jg];
                float4 w3 = Wl4[(k4 * 4 + 3) * 16 + jg];
                ACC4(a0, xv0)
                ACC4(a1, xv1)
                ACC4(a2, xv2)
                ACC4(a3, xv3)
                xv0 = nx0; xv1 = nx1; xv2 = nx2; xv3 = nx3;
            }
            float d0 = dinv[row0 + 0], d1 = dinv[row0 + 1], d2 = dinv[row0 + 2], d3 = dinv[row0 + 3];
            a0.x *= d0; a0.y *= d0; a0.z *= d0; a0.w *= d0;
            a1.x *= d1; a1.y *= d1; a1.z *= d1; a1.w *= d1;
            a2.x *= d2; a2.y *= d2; a2.z *= d2; a2.w *= d2;
            a3.x *= d3; a3.y *= d3; a3.z *= d3; a3.w *= d3;
            ((float4*)(y + (size_t)(row0 + 0) * F_OUT))[jg] = a0;
            ((float4*)(y + (size_t)(row0 + 1) * F_OUT))[jg] = a1;
            ((float4*)(y + (size_t)(row0 + 2) * F_OUT))[jg] = a2;
            ((float4*)(y + (size_t)(row0 + 3) * F_OUT))[jg] = a3;
        } else {
            // tail path (only when N % 16 != 0)
            for (int i4 = 0; i4 < 4; ++i4) {
                int row = row0 + i4;
                if (row >= N) break;
                const float4* xr = (const float4*)(x + (size_t)row * F_IN);
                float4 a = {0,0,0,0};
                for (int k4 = 0; k4 < F_IN / 4; ++k4) {
                    float4 xv = xr[k4];
                    float4 w0 = Wl4[(k4 * 4 + 0) * 16 + jg];
                    float4 w1 = Wl4[(k4 * 4 + 1) * 16 + jg];
                    float4 w2 = Wl4[(k4 * 4 + 2) * 16 + jg];
                    float4 w3 = Wl4[(k4 * 4 + 3) * 16 + jg];
                    ACC4(a, xv)
                }
                float di = dinv[row];
                a.x *= di; a.y *= di; a.z *= di; a.w *= di;
                ((float4*)(y + (size_t)row * F_OUT))[jg] = a;
            }
        }
    }
}

// ---------------- propagation in g-space: one wave per node, lane = feature ----------------
// g_out[d] = dinv[d]^2 * ( sum_e w_e * g_in[src] + g_in[d] )
__global__ __launch_bounds__(256) void prop_kernel(const float* __restrict__ gin, float* __restrict__ gout,
                                                   const int* __restrict__ ptr, const int* __restrict__ cnt,
                                                   const float* __restrict__ dinv,
                                                   const int2* __restrict__ csr, int N) {
    int node = blockIdx.x * 4 + (threadIdx.x >> 6);
    if (node >= N) return;
    int lane = threadIdx.x & 63;
    float acc = gin[(size_t)node * 64 + lane];  // self-loop, weight 1
    int p = ptr[node], c = cnt[node];
    int i = 0;
    for (; i + 8 <= c; i += 8) {
        int2 e0 = csr[p + i + 0];
        int2 e1 = csr[p + i + 1];
        int2 e2 = csr[p + i + 2];
        int2 e3 = csr[p + i + 3];
        int2 e4 = csr[p + i + 4];
        int2 e5 = csr[p + i + 5];
        int2 e6 = csr[p + i + 6];
        int2 e7 = csr[p + i + 7];
        float v0 = gin[(size_t)e0.x * 64 + lane];
        float v1 = gin[(size_t)e1.x * 64 + lane];
        float v2 = gin[(size_t)e2.x * 64 + lane];
        float v3 = gin[(size_t)e3.x * 64 + lane];
        float v4 = gin[(size_t)e4.x * 64 + lane];
        float v5 = gin[(size_t)e5.x * 64 + lane];
        float v6 = gin[(size_t)e6.x * 64 + lane];
        float v7 = gin[(size_t)e7.x * 64 + lane];
        acc = fmaf(__int_as_float(e0.y), v0, acc);
        acc = fmaf(__int_as_float(e1.y), v1, acc);
        acc = fmaf(__int_as_float(e2.y), v2, acc);
        acc = fmaf(__int_as_float(e3.y), v3, acc);
        acc = fmaf(__int_as_float(e4.y), v4, acc);
        acc = fmaf(__int_as_float(e5.y), v5, acc);
        acc = fmaf(__int_as_float(e6.y), v6, acc);
        acc = fmaf(__int_as_float(e7.y), v7, acc);
    }
    for (; i < c; ++i) {
        int2 e = csr[p + i];
        acc = fmaf(__int_as_float(e.y), gin[(size_t)e.x * 64 + lane], acc);
    }
    float di = dinv[node];
    gout[(size_t)node * 64 + lane] = acc * di * di;
}

// ---------------- hop 3 fused with epilogue ----------------
// logits = acc * dinv[d]  (= g3/dinv);  out = log_softmax(relu(logits + b))
__global__ __launch_bounds__(256) void prop_final_kernel(const float* __restrict__ gin, float* __restrict__ out,
                                                         const int* __restrict__ ptr, const int* __restrict__ cnt,
                                                         const float* __restrict__ dinv,
                                                         const int2* __restrict__ csr,
                                                         const float* __restrict__ b, int N) {
    int node = blockIdx.x * 4 + (threadIdx.x >> 6);
    if (node >= N) return;
    int lane = threadIdx.x & 63;
    float acc = gin[(size_t)node * 64 + lane];
    int p = ptr[node], c = cnt[node];
    int i = 0;
    for (; i + 8 <= c; i += 8) {
        int2 e0 = csr[p + i + 0];
        int2 e1 = csr[p + i + 1];
        int2 e2 = csr[p + i + 2];
        int2 e3 = csr[p + i + 3];
        int2 e4 = csr[p + i + 4];
        int2 e5 = csr[p + i + 5];
        int2 e6 = csr[p + i + 6];
        int2 e7 = csr[p + i + 7];
        float v0 = gin[(size_t)e0.x * 64 + lane];
        float v1 = gin[(size_t)e1.x * 64 + lane];
        float v2 = gin[(size_t)e2.x * 64 + lane];
        float v3 = gin[(size_t)e3.x * 64 + lane];
        float v4 = gin[(size_t)e4.x * 64 + lane];
        float v5 = gin[(size_t)e5.x * 64 + lane];
        float v6 = gin[(size_t)e6.x * 64 + lane];
        float v7 = gin[(size_t)e7.x * 64 + lane];
        acc = fmaf(__int_as_float(e0.y), v0, acc);
        acc = fmaf(__int_as_float(e1.y), v1, acc);
        acc = fmaf(__int_as_float(e2.y), v2, acc);
        acc = fmaf(__int_as_float(e3.y), v3, acc);
        acc = fmaf(__int_as_float(e4.y), v4, acc);
        acc = fmaf(__int_as_float(e5.y), v5, acc);
        acc = fmaf(__int_as_float(e6.y), v6, acc);
        acc = fmaf(__int_as_float(e7.y), v7, acc);
    }
    for (; i < c; ++i) {
        int2 e = csr[p + i];
        acc = fmaf(__int_as_float(e.y), gin[(size_t)e.x * 64 + lane], acc);
    }
    float v = acc * dinv[node] + b[lane];   // h3 = g3/dinv = (acc*di^2)/di = acc*di
    v = fmaxf(v, 0.0f);
    float m = v;
    for (int off = 32; off; off >>= 1) m = fmaxf(m, __shfl_xor(m, off, 64));
    float ex = expf(v - m);
    float s = ex;
    for (int off = 32; off; off >>= 1) s += __shfl_xor(s, off, 64);
    out[(size_t)node * 64 + lane] = (v - m) - logf(s);
}

// ---------------- launch ----------------

extern "C" void kernel_launch(void* const* d_in, const int* in_sizes, int n_in,
                              void* d_out, int out_size, void* d_ws, size_t ws_size,
                              hipStream_t stream) {
    const float* x = (const float*)d_in[0];
    const float* edge_attr = (const float*)d_in[1];
    const float* W = (const float*)d_in[2];
    const float* b = (const float*)d_in[3];
    const int* ei = (const int*)d_in[4];   // harness delivers integer inputs as int32
    int N = in_sizes[0] / F_IN;
    int E = in_sizes[4] / 2;
    float* out = (float*)d_out;

    char* ws = (char*)d_ws;
    size_t off = 0;
    auto alloc = [&](size_t bytes) -> char* {
        char* p = ws + off;
        off += (bytes + 255) & ~(size_t)255;
        return p;
    };
    float* dinv    = (float*)alloc((size_t)N * 4);
    int*   cnt     = (int*)alloc((size_t)N * 4);
    int*   ptr     = (int*)alloc((size_t)N * 4);
    int*   bsum    = (int*)alloc(256 * 4);
    int*   bscan   = (int*)alloc(256 * 4);
    float* w       = (float*)alloc((size_t)E * 4);
    int*   seq     = (int*)alloc((size_t)E * 4);
    int2*  csr     = (int2*)alloc((size_t)E * 8);
    float* h0      = (float*)alloc((size_t)N * 64 * 4);
    float* h1      = (float*)alloc((size_t)N * 64 * 4);
    // total ~77 MB of ws

    int nbN = (N + 255) / 256;
    int nbE = (E + 255) / 256;
    int nb1024 = (N + 1023) / 1024;
    int nbNode4 = (N + 3) / 4;
    int ngroups = (N + 15) / 16;
    int nbXW = (ngroups + 7) / 8;   // 8 waves per 512-thread block, 1 group/wave

    init_kernel<<<nbN, 256, 0, stream>>>(cnt, N);
    pass1_kernel<<<nbE, 256, 0, stream>>>(edge_attr, ei + E, E, N, w, seq, cnt);
    scan1_kernel<<<nb1024, 256, 0, stream>>>(cnt, ptr, bsum, N);
    scan2_kernel<<<1, 256, 0, stream>>>(bsum, bscan, nb1024);
    scan3_kernel<<<nbN, 256, 0, stream>>>(ptr, bscan, N);
    pass2_kernel<<<nbE, 256, 0, stream>>>(ei, w, seq, ptr, csr, E, N);
    degk_kernel<<<nbN, 256, 0, stream>>>(ptr, cnt, csr, dinv, N);

    xw_kernel<<<nbXW, 512, 0, stream>>>(x, W, dinv, h0, N);

    // hops 1,2 ping-pong; hop 3 fused with epilogue writes d_out
    prop_kernel<<<nbNode4, 256, 0, stream>>>(h0, h1, ptr, cnt, dinv, csr, N);
    prop_kernel<<<nbNode4, 256, 0, stream>>>(h1, h0, ptr, cnt, dinv, csr, N);
    prop_final_kernel<<<nbNode4, 256, 0, stream>>>(h0, out, ptr, cnt, dinv, csr, b, N);
}